// Round 7
// baseline (830.436 us; speedup 1.0000x reference)
//
#include <hip/hip_runtime.h>
#include <math.h>

#define N_NODES 50000
#define N_EDGES 800000
#define D 128
#define E_FEAT 16
#define NLAYERS 3
#define BN_EPS 1e-5f
#define INV_SQRT2 0.70710678118654752f

typedef __attribute__((ext_vector_type(8))) short short8;
typedef __attribute__((ext_vector_type(4))) float f32x4;

// Branchless erf (A&S 7.1.26, |err|<=1.5e-7) — used in MLP/BN (accuracy-critical path)
__device__ __forceinline__ float gelu_fast(float v) {
    const float u = v * INV_SQRT2;
    const float a = __builtin_fabsf(u);
    const float t = __builtin_amdgcn_rcpf(__builtin_fmaf(0.3275911f, a, 1.0f));
    float p = __builtin_fmaf(1.061405429f, t, -1.453152027f);
    p = __builtin_fmaf(p, t, 1.421413741f);
    p = __builtin_fmaf(p, t, -0.284496736f);
    p = __builtin_fmaf(p, t, 0.254829592f);
    p = p * t;
    const float e = __builtin_amdgcn_exp2f(-1.4426950408889634f * a * a);
    const float erf_a = __builtin_fmaf(-p, e, 1.0f);
    const float erf_u = __builtin_copysignf(erf_a, u);
    return 0.5f * v * (1.0f + erf_u);
}

// tanh-form gelu (~9 instr, |err| ~1e-3) — used only in the 307M-eval aggregate
__device__ __forceinline__ float gelu_tanh(float x) {
    const float x2 = x * x;
    const float z = x * __builtin_fmaf(0.0356774081f, x2, 0.7978845608f);
    const float E = __builtin_amdgcn_exp2f(z * 2.885390082f);      // exp(2z)
    const float r = __builtin_amdgcn_rcpf(E + 1.0f);
    const float th = __builtin_fmaf(-2.0f, r, 1.0f);               // tanh(z)
    return 0.5f * x * (1.0f + th);
}

__device__ __forceinline__ unsigned short f2bf(float f) {
    unsigned u = __float_as_uint(f);
    unsigned r = (u + 0x7FFFu + ((u >> 16) & 1u)) >> 16;
    return (unsigned short)r;
}
__device__ __forceinline__ float bf2f_lo(unsigned u) { return __uint_as_float(u << 16); }
__device__ __forceinline__ float bf2f_hi(unsigned u) { return __uint_as_float(u & 0xFFFF0000u); }

// ---------------- CSR build ----------------
__global__ __launch_bounds__(256) void count_kernel(const int* __restrict__ dst,
                                                    int* __restrict__ counts) {
    int e = blockIdx.x * 256 + threadIdx.x;
    if (e < N_EDGES) atomicAdd(&counts[dst[e]], 1);
}

#define NSCAN_BLOCKS 196
__global__ __launch_bounds__(256) void scan1_kernel(const int* __restrict__ counts,
                                                    int* __restrict__ offsets,
                                                    int* __restrict__ bsum) {
    __shared__ int wsum[4];
    __shared__ int wexcl[4];
    const int t = threadIdx.x, lane = t & 63, wid = t >> 6;
    const int idx = blockIdx.x * 256 + t;
    int v = (idx < N_NODES) ? counts[idx] : 0;
    int incl = v;
    #pragma unroll
    for (int off = 1; off < 64; off <<= 1) {
        int u = __shfl_up(incl, off, 64);
        if (lane >= off) incl += u;
    }
    if (lane == 63) wsum[wid] = incl;
    __syncthreads();
    if (t == 0) {
        int r = 0;
        #pragma unroll
        for (int g = 0; g < 4; ++g) { wexcl[g] = r; r += wsum[g]; }
        bsum[blockIdx.x] = r;
    }
    __syncthreads();
    if (idx < N_NODES) offsets[idx] = wexcl[wid] + (incl - v);
}

__global__ __launch_bounds__(256) void scan2_kernel(const int* __restrict__ bsum,
                                                    int* __restrict__ bbase,
                                                    int* __restrict__ offsets) {
    __shared__ int wsum[4];
    __shared__ int wexcl[4];
    const int t = threadIdx.x, lane = t & 63, wid = t >> 6;
    int v = (t < NSCAN_BLOCKS) ? bsum[t] : 0;
    int incl = v;
    #pragma unroll
    for (int off = 1; off < 64; off <<= 1) {
        int u = __shfl_up(incl, off, 64);
        if (lane >= off) incl += u;
    }
    if (lane == 63) wsum[wid] = incl;
    __syncthreads();
    if (t == 0) {
        int r = 0;
        #pragma unroll
        for (int g = 0; g < 4; ++g) { wexcl[g] = r; r += wsum[g]; }
        offsets[N_NODES] = r;
    }
    __syncthreads();
    if (t < NSCAN_BLOCKS) bbase[t] = wexcl[wid] + (incl - v);
}

__global__ __launch_bounds__(256) void scan3_kernel(int* __restrict__ offsets,
                                                    const int* __restrict__ bbase,
                                                    int* __restrict__ cursor) {
    const int idx = blockIdx.x * 256 + threadIdx.x;
    if (idx < N_NODES) {
        const int o = offsets[idx] + bbase[blockIdx.x];
        offsets[idx] = o;
        cursor[idx] = o;
    }
}

__global__ __launch_bounds__(256) void scatter_kernel(const int* __restrict__ dst,
                                                      int* __restrict__ cursor,
                                                      int* __restrict__ sorted_eid) {
    int e = blockIdx.x * 256 + threadIdx.x;
    if (e < N_EDGES) {
        int p = atomicAdd(&cursor[dst[e]], 1);
        sorted_eid[p] = e;
    }
}

// permute + edge-embedding precompute (layer-invariant!):
// sorted_emb[p][c] = bf16( be[c] + ea[eid_p]@We[:,c] ), plus sorted_src/ew.
// One wave per sorted position; lane owns 2 features.
#define PE_BLOCKS 2048
#define PE_WAVES (PE_BLOCKS * 4)
__global__ __launch_bounds__(256, 4) void permute_emb_kernel(
    const int* __restrict__ sorted_eid,
    const int* __restrict__ src,
    const float* __restrict__ ew,
    const float* __restrict__ ea,
    const float* __restrict__ We,
    const float* __restrict__ be,
    int* __restrict__ sorted_src,
    float* __restrict__ sorted_ew,
    unsigned int* __restrict__ sorted_emb)   // E x 64 dwords (2 bf16 each)
{
    const int t = threadIdx.x;
    const int lane = t & 63;
    const int gw = blockIdx.x * 4 + (t >> 6);
    const int c0 = lane * 2;

    float2 wreg[E_FEAT];
    #pragma unroll
    for (int k = 0; k < E_FEAT; ++k)
        wreg[k] = *(const float2*)&We[k * D + c0];
    const float2 bev = *(const float2*)&be[c0];

    for (int p = gw; p < N_EDGES; p += PE_WAVES) {
        const int eid = __builtin_amdgcn_readfirstlane(sorted_eid[p]);
        const int s   = __builtin_amdgcn_readfirstlane(src[eid]);
        const float w = ew[eid];
        const float* __restrict__ ear = ea + (size_t)eid * E_FEAT;
        float m0 = bev.x, m1 = bev.y;
        #pragma unroll
        for (int k = 0; k < E_FEAT; ++k) {
            const float eak = ear[k];
            m0 = __builtin_fmaf(eak, wreg[k].x, m0);
            m1 = __builtin_fmaf(eak, wreg[k].y, m1);
        }
        const unsigned int packed = (unsigned int)f2bf(m0) | ((unsigned int)f2bf(m1) << 16);
        sorted_emb[(size_t)p * 64 + lane] = packed;
        if (lane == 0) { sorted_src[p] = s; sorted_ew[p] = w; }
    }
}

// pack W (K x N, row-major) into MFMA B-fragment order, bf16
__global__ __launch_bounds__(256) void pack_kernel(const float* __restrict__ W1,
                                                   const float* __restrict__ W2,
                                                   unsigned short* __restrict__ Wp) {
    const int idx = blockIdx.x * 256 + threadIdx.x;   // 6*2048 = 12288 items
    if (idx >= 6 * 2048) return;
    const int m    = idx >> 11;
    const int rem  = idx & 2047;
    const int ct   = rem >> 8;
    const int rem2 = rem & 255;
    const int kt   = rem2 >> 6;
    const int lane = rem2 & 63;
    const float* Wsrc = (m < 3) ? (W1 + (size_t)m * D * D)
                                : (W2 + (size_t)(m - 3) * D * D);
    const int k0  = kt * 32 + (lane >> 4) * 8;
    const int col = ct * 16 + (lane & 15);
    unsigned short o[8];
    #pragma unroll
    for (int j = 0; j < 8; ++j) o[j] = f2bf(Wsrc[(size_t)(k0 + j) * D + col]);
    unsigned short* d = Wp + (size_t)idx * 8;
    #pragma unroll
    for (int j = 0; j < 8; ++j) d[j] = o[j];
}

// ---------------- aggregation: one wave per node, precomputed emb ----------------
// preb[n] = bf16( (1+eps)*x[n] + sum_e gelu(x[src_e] + emb_e) * ew_e )
__global__ __launch_bounds__(256, 8) void aggregate_kernel(
    const float* __restrict__ x,
    const int* __restrict__ sorted_src,
    const float* __restrict__ sorted_ew,
    const unsigned int* __restrict__ sorted_emb,
    const int* __restrict__ offsets,
    const float* __restrict__ eps_p,
    unsigned int* __restrict__ preb)       // N x 64 dwords (bf16 pairs)
{
    const int t = threadIdx.x;
    const int lane = t & 63;
    const int node = blockIdx.x * 4 + (t >> 6);   // 12500 blocks
    const int c0 = lane * 2;
    const float e1 = 1.0f + *eps_p;

    const int start = __builtin_amdgcn_readfirstlane(offsets[node]);
    const int end   = __builtin_amdgcn_readfirstlane(offsets[node + 1]);

    float a0 = 0.0f, a1 = 0.0f;
    int p = start;
    for (; p + 2 <= end; p += 2) {
        const int s0 = __builtin_amdgcn_readfirstlane(sorted_src[p]);
        const int s1 = __builtin_amdgcn_readfirstlane(sorted_src[p + 1]);
        const float2 x0 = *(const float2*)&x[(size_t)s0 * D + c0];
        const float2 x1 = *(const float2*)&x[(size_t)s1 * D + c0];
        const unsigned int e0 = sorted_emb[(size_t)p * 64 + lane];
        const unsigned int e1u = sorted_emb[(size_t)(p + 1) * 64 + lane];
        const float w0 = sorted_ew[p];
        const float w1 = sorted_ew[p + 1];
        a0 = __builtin_fmaf(gelu_tanh(x0.x + bf2f_lo(e0)),  w0, a0);
        a1 = __builtin_fmaf(gelu_tanh(x0.y + bf2f_hi(e0)),  w0, a1);
        a0 = __builtin_fmaf(gelu_tanh(x1.x + bf2f_lo(e1u)), w1, a0);
        a1 = __builtin_fmaf(gelu_tanh(x1.y + bf2f_hi(e1u)), w1, a1);
    }
    if (p < end) {
        const int s0 = __builtin_amdgcn_readfirstlane(sorted_src[p]);
        const float2 x0 = *(const float2*)&x[(size_t)s0 * D + c0];
        const unsigned int e0 = sorted_emb[(size_t)p * 64 + lane];
        const float w0 = sorted_ew[p];
        a0 = __builtin_fmaf(gelu_tanh(x0.x + bf2f_lo(e0)), w0, a0);
        a1 = __builtin_fmaf(gelu_tanh(x0.y + bf2f_hi(e0)), w0, a1);
    }

    const float2 xnode = *(const float2*)&x[(size_t)node * D + c0];
    const float o0 = __builtin_fmaf(e1, xnode.x, a0);
    const float o1 = __builtin_fmaf(e1, xnode.y, a1);
    preb[(size_t)node * 64 + lane] = (unsigned int)f2bf(o0) | ((unsigned int)f2bf(o1) << 16);
}

// ---------------- fused MLP via bf16 MFMA (pre already bf16) ----------------
#define GM 64
#define LDB 136   // ushort leading dim: 272 B row stride -> free 2-way LDS pattern

__global__ __launch_bounds__(256, 4) void mlp_fused_kernel(
    const unsigned short* __restrict__ preb,   // N x D bf16
    const unsigned short* __restrict__ Wp1,
    const float* __restrict__ b1,
    const unsigned short* __restrict__ Wp2,
    const float* __restrict__ b2,
    unsigned short* __restrict__ Hb,           // N x D bf16 (may alias preb)
    float* __restrict__ colsum,
    float* __restrict__ colsumsq)
{
    __shared__ __align__(16) unsigned short sAb[GM * LDB];  // 17408 B
    __shared__ float sred[2][4][D];                         // 4096 B
    const int t = threadIdx.x;
    const int row0 = blockIdx.x * GM;

    // stage pre tile (already bf16, straight copy)
    for (int i = t; i < GM * (D / 8); i += 256) {
        const int r  = i / (D / 8);
        const int cc = (i % (D / 8)) * 8;
        const int gr = row0 + r;
        uint4 v;
        if (gr < N_NODES) v = *(const uint4*)&preb[(size_t)gr * D + cc];
        else { v.x = v.y = v.z = v.w = 0u; }
        *(uint4*)&sAb[r * LDB + cc] = v;
    }
    __syncthreads();

    const int wave = t >> 6, lane = t & 63;
    const int m0   = wave * 16;
    const int mrow = lane & 15;
    const int q    = lane >> 4;
    const int colb = lane & 15;

    short8 a[4];
    #pragma unroll
    for (int kt = 0; kt < 4; ++kt)
        a[kt] = *(const short8*)&sAb[(m0 + mrow) * LDB + kt * 32 + q * 8];

    // ---- GEMM 1 ----
    f32x4 acc[8];
    #pragma unroll
    for (int ct = 0; ct < 8; ++ct) acc[ct] = (f32x4){0.f, 0.f, 0.f, 0.f};
    #pragma unroll
    for (int ct = 0; ct < 8; ++ct) {
        #pragma unroll
        for (int kt = 0; kt < 4; ++kt) {
            const short8 b = *(const short8*)&Wp1[((size_t)(ct * 4 + kt) * 64 + lane) * 8];
            acc[ct] = __builtin_amdgcn_mfma_f32_16x16x32_bf16(a[kt], b, acc[ct], 0, 0, 0);
        }
    }

    // gelu(acc + b1) -> back into own slab as bf16 (same-wave RAW, no barrier)
    #pragma unroll
    for (int ct = 0; ct < 8; ++ct) {
        const float bb = b1[ct * 16 + colb];
        #pragma unroll
        for (int r = 0; r < 4; ++r) {
            const float o = gelu_fast(acc[ct][r] + bb);
            sAb[(m0 + q * 4 + r) * LDB + ct * 16 + colb] = f2bf(o);
        }
    }

    // ---- GEMM 2 ----
    #pragma unroll
    for (int kt = 0; kt < 4; ++kt)
        a[kt] = *(const short8*)&sAb[(m0 + mrow) * LDB + kt * 32 + q * 8];
    #pragma unroll
    for (int ct = 0; ct < 8; ++ct) acc[ct] = (f32x4){0.f, 0.f, 0.f, 0.f};
    #pragma unroll
    for (int ct = 0; ct < 8; ++ct) {
        #pragma unroll
        for (int kt = 0; kt < 4; ++kt) {
            const short8 b = *(const short8*)&Wp2[((size_t)(ct * 4 + kt) * 64 + lane) * 8];
            acc[ct] = __builtin_amdgcn_mfma_f32_16x16x32_bf16(a[kt], b, acc[ct], 0, 0, 0);
        }
    }

    // epilogue: + b2, store Hb (bf16), column stats from fp32
    #pragma unroll
    for (int ct = 0; ct < 8; ++ct) {
        const float bb = b2[ct * 16 + colb];
        float ssum = 0.f, qsum = 0.f;
        #pragma unroll
        for (int r = 0; r < 4; ++r) {
            const int grow = row0 + m0 + q * 4 + r;
            const float o = acc[ct][r] + bb;
            if (grow < N_NODES) {
                Hb[(size_t)grow * D + ct * 16 + colb] = f2bf(o);
                ssum += o;
                qsum += o * o;
            }
        }
        ssum += __shfl_xor(ssum, 16, 64);
        ssum += __shfl_xor(ssum, 32, 64);
        qsum += __shfl_xor(qsum, 16, 64);
        qsum += __shfl_xor(qsum, 32, 64);
        if (q == 0) {
            sred[0][wave][ct * 16 + colb] = ssum;
            sred[1][wave][ct * 16 + colb] = qsum;
        }
    }
    __syncthreads();
    if (t < D) {
        const float ss = sred[0][0][t] + sred[0][1][t] + sred[0][2][t] + sred[0][3][t];
        const float qq = sred[1][0][t] + sred[1][1][t] + sred[1][2][t] + sred[1][3][t];
        atomicAdd(&colsum[t], ss);
        atomicAdd(&colsumsq[t], qq);
    }
}

// ---------------- BN apply + gelu + residual ----------------
__global__ __launch_bounds__(256) void bn_apply_kernel(
    const unsigned short* __restrict__ Hb,
    const float* __restrict__ colsum,
    const float* __restrict__ colsumsq,
    const float* __restrict__ gamma,
    const float* __restrict__ beta,
    const float* __restrict__ x_in,
    float* __restrict__ x_out)
{
    const int idx = blockIdx.x * 256 + threadIdx.x;   // N*D/4 threads
    const int c0 = (idx & 31) * 4;
    const float invN = 1.0f / (float)N_NODES;

    const float4 s  = *(const float4*)&colsum[c0];
    const float4 q  = *(const float4*)&colsumsq[c0];
    const float4 g  = *(const float4*)&gamma[c0];
    const float4 bt = *(const float4*)&beta[c0];
    const ushort4 hb = *(const ushort4*)&Hb[(size_t)idx * 4];
    const float4 xv = *(const float4*)&x_in[(size_t)idx * 4];

    float4 o;
    {
        float h = __uint_as_float((unsigned)hb.x << 16);
        float mu = s.x * invN, var = q.x * invN - mu * mu;
        float hn = (h - mu) * rsqrtf(var + BN_EPS) * g.x + bt.x;
        o.x = (xv.x + gelu_fast(hn)) * INV_SQRT2;
    }
    {
        float h = __uint_as_float((unsigned)hb.y << 16);
        float mu = s.y * invN, var = q.y * invN - mu * mu;
        float hn = (h - mu) * rsqrtf(var + BN_EPS) * g.y + bt.y;
        o.y = (xv.y + gelu_fast(hn)) * INV_SQRT2;
    }
    {
        float h = __uint_as_float((unsigned)hb.z << 16);
        float mu = s.z * invN, var = q.z * invN - mu * mu;
        float hn = (h - mu) * rsqrtf(var + BN_EPS) * g.z + bt.z;
        o.z = (xv.z + gelu_fast(hn)) * INV_SQRT2;
    }
    {
        float h = __uint_as_float((unsigned)hb.w << 16);
        float mu = s.w * invN, var = q.w * invN - mu * mu;
        float hn = (h - mu) * rsqrtf(var + BN_EPS) * g.w + bt.w;
        o.w = (xv.w + gelu_fast(hn)) * INV_SQRT2;
    }
    *(float4*)&x_out[(size_t)idx * 4] = o;
}

extern "C" void kernel_launch(void* const* d_in, const int* in_sizes, int n_in,
                              void* d_out, int out_size, void* d_ws, size_t ws_size,
                              hipStream_t stream) {
    const float* x_in  = (const float*)d_in[0];
    const int*   ei    = (const int*)d_in[1];
    const float* ea    = (const float*)d_in[2];
    const float* ew    = (const float*)d_in[3];
    const float* We    = (const float*)d_in[4];
    const float* be    = (const float*)d_in[5];
    const float* W1    = (const float*)d_in[6];
    const float* b1    = (const float*)d_in[7];
    const float* W2    = (const float*)d_in[8];
    const float* b2    = (const float*)d_in[9];
    const float* eps   = (const float*)d_in[10];
    const float* gamma = (const float*)d_in[11];
    const float* beta  = (const float*)d_in[12];

    const int* src = ei;
    const int* dst = ei + N_EDGES;

    float* xcur = (float*)d_out;

    // ws layout (dwords unless noted):
    // [counts 50000][colsum_all 384f][colsumsq_all 384f][cursor 50000]
    // [offsets 50004][bsum 256][bbase 256][sorted_eid 800000]
    // [sorted_src 800000][sorted_ew 800000f][Wpack 49152]
    // [sorted_emb 51.2M dwords (204.8 MB)][preb/Hb 3.2M dwords (12.8 MB)]
    int*   counts       = (int*)d_ws;
    float* colsum_all   = (float*)(counts + N_NODES);
    float* colsumsq_all = colsum_all + NLAYERS * D;
    int*   cursor       = (int*)(colsumsq_all + NLAYERS * D);
    int*   offsets      = cursor + N_NODES;
    int*   bsum         = offsets + N_NODES + 4;
    int*   bbase        = bsum + 256;
    int*   sorted_eid   = bbase + 256;
    int*   sorted_src   = sorted_eid + N_EDGES;
    float* sorted_ew    = (float*)(sorted_src + N_EDGES);
    unsigned short* Wpack = (unsigned short*)(sorted_ew + N_EDGES);
    unsigned int* sorted_emb = (unsigned int*)(Wpack + 6 * 2048 * 8);
    unsigned int* preb_u  = sorted_emb + (size_t)N_EDGES * 64;
    unsigned short* preb  = (unsigned short*)preb_u;
    unsigned short* Hb    = preb;   // alias: each block reads its pre rows before writing same H rows

    hipMemsetAsync(counts, 0, sizeof(int) * (N_NODES + 2 * NLAYERS * D), stream);
    count_kernel<<<(N_EDGES + 255) / 256, 256, 0, stream>>>(dst, counts);
    scan1_kernel<<<NSCAN_BLOCKS, 256, 0, stream>>>(counts, offsets, bsum);
    scan2_kernel<<<1, 256, 0, stream>>>(bsum, bbase, offsets);
    scan3_kernel<<<NSCAN_BLOCKS, 256, 0, stream>>>(offsets, bbase, cursor);
    scatter_kernel<<<(N_EDGES + 255) / 256, 256, 0, stream>>>(dst, cursor, sorted_eid);
    permute_emb_kernel<<<PE_BLOCKS, 256, 0, stream>>>(
        sorted_eid, src, ew, ea, We, be, sorted_src, sorted_ew, sorted_emb);
    pack_kernel<<<48, 256, 0, stream>>>(W1, W2, Wpack);

    const int mlp_blocks = (N_NODES + GM - 1) / GM;   // 782
    const int bn_blocks  = (N_NODES * D / 4) / 256;   // 6250
    const int agg_blocks = N_NODES / 4;               // 12500

    for (int i = 0; i < NLAYERS; ++i) {
        const float* xl = (i == 0) ? x_in : xcur;
        aggregate_kernel<<<agg_blocks, 256, 0, stream>>>(
            xl, sorted_src, sorted_ew, sorted_emb, offsets, eps + i, preb_u);
        mlp_fused_kernel<<<mlp_blocks, 256, 0, stream>>>(
            preb, Wpack + (size_t)i * 16384, b1 + (size_t)i * D,
            Wpack + (size_t)(3 + i) * 16384, b2 + (size_t)i * D,
            Hb, colsum_all + i * D, colsumsq_all + i * D);
        bn_apply_kernel<<<bn_blocks, 256, 0, stream>>>(
            Hb, colsum_all + i * D, colsumsq_all + i * D,
            gamma + (size_t)i * D, beta + (size_t)i * D, xl, xcur);
    }
}